// Round 18
// baseline (216.357 us; speedup 1.0000x reference)
//
#include <hip/hip_runtime.h>
#include <hip/hip_bf16.h>

typedef __bf16 bf16x8 __attribute__((ext_vector_type(8)));
typedef float  f32x4  __attribute__((ext_vector_type(4)));
typedef float  f32x16 __attribute__((ext_vector_type(16)));

#define HW       3136
#define IMG_W    56
#define IMG_H    56
#define WGRAN    (9*128*16)                // 16B granules in W (18432)
#define WB_BYTES ((size_t)WGRAN*16)        // 294912
#define CBLK     800                       // 32 img x 25 flat 128-pos tiles
#define SLOT_B   9216                      // 64 cols * 144 B (64ch half + 16B pad)
#define LDS_B    (6*SLOT_B)                // 55296

#define AS1 __attribute__((address_space(1)))
#define AS3 __attribute__((address_space(3)))

// ---- weight fp32 -> bf16, 32x32-fragment-major:
//      granule i = (((tap*8 + kg)*2 + o)*2 + f)*64 + lane ;
//      lane l holds oc = o*64 + f*32 + (l&31), ch = kg*16 + (l>>5)*8 .. +7 ----
__global__ __launch_bounds__(256) void wcvt_kernel(const float* __restrict__ w,
                                                   unsigned char* __restrict__ wb) {
    int i = blockIdx.x * 256 + threadIdx.x;
    if (i >= WGRAN) return;
    const int l = i & 63, f = (i >> 6) & 1, o = (i >> 7) & 1;
    const int kg = (i >> 8) & 7, tap = i >> 11;
    const int oc = o * 64 + f * 32 + (l & 31);
    const int ch = kg * 16 + (l >> 5) * 8;
    const float* src = w + (size_t)(tap * 128 + oc) * 128 + ch;
    bf16x8 v;
    #pragma unroll
    for (int j = 0; j < 8; ++j) v[j] = (__bf16)src[j];
    *(bf16x8*)(wb + (size_t)i * 16) = v;
}

// ---- stage one (slot, granule) of channel-half H: 8 coalesced 224B fp32 rows ->
//      cvt -> one ds_write_b128 at pitch-144. Zero borders via mask. ----
template<int H>
__device__ __forceinline__ void stage_task(unsigned char* xs, const float* __restrict__ xn,
                                           int obase, int s, int g, int lane) {
    const int ar  = obase - 1 + s;                       // absolute image row
    const int arc = min(max(ar, 0), IMG_H - 1);
    const int wcc = min(max(lane - 1, 0), IMG_W - 1);
    const bool v  = (ar >= 0) & (ar < IMG_H) & (lane >= 1) & (lane <= IMG_W);
    const float* bp = xn + (size_t)(H * 64 + g * 8) * HW + arc * IMG_W + wcc;
    bf16x8 pk;
    #pragma unroll
    for (int j = 0; j < 8; ++j) {
        float f = bp[(size_t)j * HW];
        pk[j] = (__bf16)(v ? f : 0.f);
    }
    *(bf16x8*)(xs + s * SLOT_B + lane * 144 + g * 16) = pk;
}

// ---- compute 36 (tap,k) steps of channel-half H: 1 B-read -> 2x mfma_32x32x16;
//      A ring (1 step ahead, from L2), B ring (4 deep, from LDS).
//      vb is 0-based: slot = (prow-obase) + tap/3  ==  image row prow + (tap/3 - 1);
//      staged col = pcol + tap%3  ==  image col pcol + (tap%3 - 1). ----
template<int H>
__device__ __forceinline__ void compute_half(const unsigned char* xs, const unsigned char* wA,
                                             f32x16& acc0, f32x16& acc1, int vb) {
    bf16x8 aB[2][2], bB[4];
    #pragma unroll
    for (int f = 0; f < 2; ++f)
        aB[0][f] = *(const bf16x8*)(wA + (0 * 8 + H * 4 + 0) * 4096 + f * 1024);
    #pragma unroll
    for (int j = 0; j < 4; ++j) {                        // steps 0..3 are tap 0
        bB[j] = *(const bf16x8*)(xs + vb + (j & 3) * 32);
    }

    #pragma unroll
    for (int j = 0; j < 36; ++j) {
        if (j < 35) {                                    // prefetch next step's A (L2)
            const int t2 = (j + 1) >> 2, k2 = (j + 1) & 3;
            #pragma unroll
            for (int f = 0; f < 2; ++f)
                aB[(j + 1) & 1][f] = *(const bf16x8*)(wA + (t2 * 8 + H * 4 + k2) * 4096 + f * 1024);
        }
        __builtin_amdgcn_sched_barrier(0);
        __builtin_amdgcn_s_setprio(1);
        acc0 = __builtin_amdgcn_mfma_f32_32x32x16_bf16(aB[j & 1][0], bB[j & 3], acc0, 0, 0, 0);
        acc1 = __builtin_amdgcn_mfma_f32_32x32x16_bf16(aB[j & 1][1], bB[j & 3], acc1, 0, 0, 0);
        if (j + 4 < 36) {                                // refill B ring 4 ahead (LDS)
            const int t2 = (j + 4) >> 2, k2 = (j + 4) & 3;
            bB[j & 3] = *(const bf16x8*)(xs + vb + (t2 / 3) * SLOT_B + (t2 % 3) * 144 + k2 * 32);
        }
        __builtin_amdgcn_s_setprio(0);
        __builtin_amdgcn_sched_barrier(0);
    }
}

// ---- conv: 800 blocks x flat 128-pos tile; 8 waves = 2 oc-halves x 4 pos-slices;
//      wave = 64 oc x 32 pos (2 MFMA / B-read); channel-half LDS 55KB, 2 blk/CU ----
__global__ __launch_bounds__(512, 4) void conv_kernel(const float* __restrict__ x,
                                                      const unsigned char* __restrict__ wb,
                                                      float* __restrict__ out) {
    __shared__ __align__(16) unsigned char xs[LDS_B];    // 6 row-slots x 64 col x 144B
    const int t = threadIdx.x, lane = t & 63, wv = t >> 6;  // 8 waves
    const int l31 = lane & 31, lh = lane >> 5;
    const int b = blockIdx.x;
    const int swz = (b & 7) * 100 + (b >> 3);            // XCD-contiguous: 4 img/XCD
    const int img = swz / 25, til = swz - img * 25;
    const int P0 = min(til * 128, HW - 128);             // last tile overlaps (idempotent)
    const int obase = P0 / 56;                           // staged rows obase-1..obase+4

    const float* xn = x + (size_t)img * 128 * HW;
    const int o = wv & 1, slice = wv >> 1;

    const int pg   = P0 + slice * 32 + l31;              // this lane's output pos
    const int prow = pg / 56, pcol = pg - prow * 56;
    const int vb   = (prow - obase) * SLOT_B + pcol * 144 + lh * 16;   // 0-based (fix)

    const unsigned char* wA = wb + o * 2048 + lane * 16;

    f32x16 acc0 = {}, acc1 = {};

    // ---- half 0: stage (48 tasks, 6/wave), compute ----
    #pragma unroll
    for (int i = 0; i < 6; ++i) {
        int task = wv + 8 * i;                           // 0..47
        stage_task<0>(xs, xn, obase, task >> 3, task & 7, lane);
    }
    __syncthreads();
    compute_half<0>(xs, wA, acc0, acc1, vb);
    __syncthreads();                                     // all waves done reading h0

    // ---- half 1 ----
    #pragma unroll
    for (int i = 0; i < 6; ++i) {
        int task = wv + 8 * i;
        stage_task<1>(xs, xn, obase, task >> 3, task & 7, lane);
    }
    __syncthreads();
    compute_half<1>(xs, wA, acc0, acc1, vb);

    // ---- store: D col=lane&31 (pos), row = (r&3)+8*(r>>2)+4*lh (oc within frag) ----
    float* on = out + (size_t)img * 128 * HW;
    #pragma unroll
    for (int r = 0; r < 16; ++r) {
        int ocr = (r & 3) + 8 * (r >> 2) + 4 * lh;
        on[(size_t)(o * 64 + ocr) * HW + pg]      = acc0[r];
        on[(size_t)(o * 64 + 32 + ocr) * HW + pg] = acc1[r];
    }
}

// ================= fallback (ws too small): self-contained, fp32 weights =================
#define PITCH  272
#define LDSB   (4*64*PITCH)
#define NBLK   896

template<int NPF>
__device__ __forceinline__ void fb_compute(const unsigned char* xs, const float* wf,
                                           float* on, int oc0, int pf0, int r0, int lane) {
    const int l15 = lane & 15, lq = lane >> 4;
    int spb[NPF];
    #pragma unroll
    for (int k = 0; k < NPF; ++k) {
        int p = (pf0 + k) * 16 + l15;
        int r = p / 56, w = p - r * 56;
        spb[k] = ((r + 1) * 64 + (w + 1)) * PITCH + lq * 16;
    }
    f32x4 acc[2][NPF];
    #pragma unroll
    for (int f = 0; f < 2; ++f)
        #pragma unroll
        for (int k = 0; k < NPF; ++k) acc[f][k] = (f32x4){0.f, 0.f, 0.f, 0.f};
    #pragma unroll 3
    for (int tap = 0; tap < 9; ++tap) {
        const int offb  = ((tap / 3) * 64 + (tap % 3) - 65) * PITCH;
        const int wbase = tap * 16384 + oc0 * 128 + l15 * 128 + lq * 8;
        #pragma unroll
        for (int c = 0; c < 4; ++c) {
            bf16x8 a[2];
            #pragma unroll
            for (int f = 0; f < 2; ++f) {
                const float* p = wf + wbase + f * 2048 + c * 32;
                #pragma unroll
                for (int j = 0; j < 8; ++j) a[f][j] = (__bf16)p[j];
            }
            #pragma unroll
            for (int k = 0; k < NPF; ++k) {
                bf16x8 b = *(const bf16x8*)(xs + spb[k] + offb + c * 64);
                #pragma unroll
                for (int f = 0; f < 2; ++f)
                    acc[f][k] = __builtin_amdgcn_mfma_f32_16x16x32_bf16(a[f], b, acc[f][k], 0, 0, 0);
            }
        }
    }
    #pragma unroll
    for (int f = 0; f < 2; ++f)
        #pragma unroll
        for (int k = 0; k < NPF; ++k) {
            int pos = r0 * 56 + (pf0 + k) * 16 + l15;
            int oc  = oc0 + f * 16 + lq * 4;
            #pragma unroll
            for (int rr = 0; rr < 4; ++rr)
                on[(size_t)(oc + rr) * HW + pos] = acc[f][k][rr];
        }
}

__global__ __launch_bounds__(512, 4) void fb_conv_kernel(const float* __restrict__ x,
                                                         const float* __restrict__ wf,
                                                         float* __restrict__ out) {
    __shared__ __align__(16) unsigned char xs[LDSB];
    const int tid = threadIdx.x, lane = tid & 63, wv = tid >> 6;
    const int bid = blockIdx.x;
    const int swz = (bid & 7) * (NBLK / 8) + (bid >> 3);
    const int n = swz / 28, rp = swz - n * 28, r0 = rp * 2;
    if (wv < 4) {
        const float* xn = x + (size_t)n * 128 * HW;
        const int ar = r0 - 1 + wv, wi = lane - 1;
        const bool v = (ar >= 0) & (ar < IMG_H) & (wi >= 0) & (wi < IMG_W);
        const int gc = min(max(ar, 0), IMG_H - 1) * IMG_W + min(max(wi, 0), IMG_W - 1);
        unsigned char* dst = xs + (wv * 64 + lane) * PITCH;
        #pragma unroll
        for (int cg = 0; cg < 16; ++cg) {
            bf16x8 pk;
            #pragma unroll
            for (int j = 0; j < 8; ++j) {
                float f = xn[(size_t)(cg * 8 + j) * HW + gc];
                pk[j] = (__bf16)(v ? f : 0.f);
            }
            *(bf16x8*)(dst + cg * 16) = pk;
        }
    }
    __syncthreads();
    const int oc0 = (wv & 3) * 32;
    float* on = out + (size_t)n * 128 * HW;
    if (wv < 4) fb_compute<4>(xs, wf, on, oc0, 0, r0, lane);
    else        fb_compute<3>(xs, wf, on, oc0, 4, r0, lane);
}

extern "C" void kernel_launch(void* const* d_in, const int* in_sizes, int n_in,
                              void* d_out, int out_size, void* d_ws, size_t ws_size,
                              hipStream_t stream) {
    const float* x = (const float*)d_in[0];
    const float* w = (const float*)d_in[1];
    float* out = (float*)d_out;

    if (ws_size >= WB_BYTES) {
        unsigned char* wb = (unsigned char*)d_ws;
        wcvt_kernel<<<(WGRAN + 255) / 256, 256, 0, stream>>>(w, wb);
        conv_kernel<<<CBLK, 512, 0, stream>>>(x, wb, out);
    } else {
        fb_conv_kernel<<<NBLK, 512, 0, stream>>>(x, w, out);
    }
}

// Round 19
// 49.039 us; speedup vs baseline: 4.4119x; 4.4119x over previous
//
#include <hip/hip_runtime.h>
#include <hip/hip_bf16.h>

typedef __bf16 bf16x8 __attribute__((ext_vector_type(8)));
typedef float  f32x4  __attribute__((ext_vector_type(4)));

#define HW       3136
#define IMG_W    56
#define IMG_H    56
#define WGRAN    (9*128*16)                // 16B granules in W (18432)
#define WB_BYTES ((size_t)WGRAN*16)        // 294912
#define CBLK     448                       // conv blocks: 14/img, 4 out-rows each
#define SLOT_B   9216                      // 64 cols * 144 B (64ch bf16 + 16B pad)
#define LDS_B    (6*SLOT_B)                // 55296

#define AS1 __attribute__((address_space(1)))
#define AS3 __attribute__((address_space(3)))

// ---- weight fp32 -> bf16, fragment-major [tap][q32][c][f][lq][l15] 16B granules ----
__global__ __launch_bounds__(256) void wcvt_kernel(const float* __restrict__ w,
                                                   unsigned char* __restrict__ wb) {
    int i = blockIdx.x * 256 + threadIdx.x;          // one 16B granule each
    if (i >= WGRAN) return;
    const int l15 = i & 15, lq = (i >> 4) & 3, f = (i >> 6) & 1;
    const int c   = (i >> 7) & 3, q32 = (i >> 9) & 3, tap = i >> 11;
    const int oc = q32 * 32 + f * 16 + l15;
    const int ch = c * 32 + lq * 8;
    const float* src = w + (size_t)(tap * 128 + oc) * 128 + ch;
    bf16x8 v;
    #pragma unroll
    for (int j = 0; j < 8; ++j) v[j] = (__bf16)src[j];
    *(bf16x8*)(wb + (size_t)i * 16) = v;
}

// ---- stage one (slot, granule) of channel-half H: 8 coalesced 224B fp32 rows ->
//      cvt -> one ds_write_b128 at pitch-144. Zero borders via mask. ----
template<int H>
__device__ __forceinline__ void stage_task(unsigned char* xs, const float* __restrict__ xn,
                                           int obase, int s, int g, int lane) {
    const int ar  = obase - 1 + s;                       // absolute image row
    const int arc = min(max(ar, 0), IMG_H - 1);
    const int wcc = min(max(lane - 1, 0), IMG_W - 1);
    const bool v  = (ar >= 0) & (ar < IMG_H) & (lane >= 1) & (lane <= IMG_W);
    const float* bp = xn + (size_t)(H * 64 + g * 8) * HW + arc * IMG_W + wcc;
    bf16x8 pk;
    #pragma unroll
    for (int j = 0; j < 8; ++j) {
        float f = bp[(size_t)j * HW];
        pk[j] = (__bf16)(v ? f : 0.f);
    }
    *(bf16x8*)(xs + s * SLOT_B + lane * 144 + g * 16) = pk;
}

// ---- compute 18 (tap,c) steps of channel-half H, accumulating ----
template<int H>
__device__ __forceinline__ void compute_half(const unsigned char* xs, const unsigned char* wt,
                                             f32x4 acc[2][7], const int vb[7], int lq) {
    bf16x8 aB[2][2];                                     // A ring, 1 step ahead
    #pragma unroll
    for (int f = 0; f < 2; ++f)
        aB[0][f] = *(const bf16x8*)(wt + ((H * 2) * 2 + f) * 1024);

    #pragma unroll
    for (int s = 0; s < 18; ++s) {
        const int tap = s >> 1, cl = s & 1;
        if (s < 17) {                                    // prefetch next step's A
            const int t2 = (s + 1) >> 1, c2 = (s + 1) & 1;
            #pragma unroll
            for (int f = 0; f < 2; ++f)
                aB[(s + 1) & 1][f] = *(const bf16x8*)(wt + t2 * 32768
                                                      + ((H * 2 + c2) * 2 + f) * 1024);
        }
        __builtin_amdgcn_sched_barrier(0);               // pin loads before MFMA cluster

        const int dh = tap / 3 - 1, dw = tap - (tap / 3) * 3 - 1;
        const int offb = dh * SLOT_B + dw * 144 + (cl * 4 + lq) * 16;
        __builtin_amdgcn_s_setprio(1);
        #pragma unroll
        for (int k = 0; k < 7; ++k) {
            bf16x8 b = *(const bf16x8*)(xs + vb[k] + offb);
            acc[0][k] = __builtin_amdgcn_mfma_f32_16x16x32_bf16(aB[s & 1][0], b, acc[0][k], 0, 0, 0);
            acc[1][k] = __builtin_amdgcn_mfma_f32_16x16x32_bf16(aB[s & 1][1], b, acc[1][k], 0, 0, 0);
        }
        __builtin_amdgcn_s_setprio(0);
        __builtin_amdgcn_sched_barrier(0);
    }
}

// ---- conv: 448 blocks x one 4-row tile (224 pos); 8 waves = 4 oc-groups x 2 pos-halves
//      (K=7); channel-split LDS (2 halves x 64ch, 55KB) -> 2 blocks/CU, 16 waves/CU ----
__global__ __launch_bounds__(512, 4) void conv_kernel(const float* __restrict__ x,
                                                      const unsigned char* __restrict__ wb,
                                                      float* __restrict__ out) {
    __shared__ __align__(16) unsigned char xs[LDS_B];    // 6 slots x 64 cols x 144B
    const int t = threadIdx.x, lane = t & 63, wv = t >> 6;  // 8 waves
    const int l15 = lane & 15, lq = lane >> 4;
    const int b = blockIdx.x;
    const int swz = (b & 7) * 56 + (b >> 3);             // XCD-contiguous: 4 img/XCD
    const int img = swz / 14, loc = swz - img * 14;
    const int obase = loc * 4;                           // out rows obase..obase+3

    const float* xn = x + (size_t)img * 128 * HW;
    const int q32 = wv & 3;                              // 32-oc group
    const int g7  = wv >> 2;                             // pos-half (7 frags)
    const unsigned char* wt = wb + (size_t)q32 * 8192 + lane * 16;

    int vb[7];
    #pragma unroll
    for (int k = 0; k < 7; ++k) {
        int p = (g7 * 7 + k) * 16 + l15;                 // 0..223 tile-local pos
        int pr = p / 56, pc = p - pr * 56;
        vb[k] = (pr + 1) * SLOT_B + (pc + 1) * 144;
    }

    f32x4 acc[2][7];
    #pragma unroll
    for (int f = 0; f < 2; ++f)
        #pragma unroll
        for (int k = 0; k < 7; ++k) acc[f][k] = (f32x4){0.f, 0.f, 0.f, 0.f};

    // ---- half 0: stage (48 tasks, 6/wave), compute ----
    #pragma unroll
    for (int i = 0; i < 6; ++i) {
        int task = wv + 8 * i;                           // 0..47
        stage_task<0>(xs, xn, obase, task >> 3, task & 7, lane);
    }
    __syncthreads();
    compute_half<0>(xs, wt, acc, vb, lq);
    __syncthreads();                                     // all waves done reading h0

    // ---- half 1 ----
    #pragma unroll
    for (int i = 0; i < 6; ++i) {
        int task = wv + 8 * i;
        stage_task<1>(xs, xn, obase, task >> 3, task & 7, lane);
    }
    __syncthreads();
    compute_half<1>(xs, wt, acc, vb, lq);

    // ---- store ----
    float* on = out + (size_t)img * 128 * HW;
    #pragma unroll
    for (int f = 0; f < 2; ++f)
        #pragma unroll
        for (int k = 0; k < 7; ++k) {
            int p = (g7 * 7 + k) * 16 + l15;
            int pr = p / 56, pc = p - pr * 56;
            int pos = (obase + pr) * 56 + pc;
            int oc  = q32 * 32 + f * 16 + lq * 4;
            #pragma unroll
            for (int rr = 0; rr < 4; ++rr)
                on[(size_t)(oc + rr) * HW + pos] = acc[f][k][rr];
        }
}

// ================= fallback (ws too small): self-contained, fp32 weights =================
#define PITCH  272
#define LDSB   (4*64*PITCH)
#define NBLK   896

template<int NPF>
__device__ __forceinline__ void fb_compute(const unsigned char* xs, const float* wf,
                                           float* on, int oc0, int pf0, int r0, int lane) {
    const int l15 = lane & 15, lq = lane >> 4;
    int spb[NPF];
    #pragma unroll
    for (int k = 0; k < NPF; ++k) {
        int p = (pf0 + k) * 16 + l15;
        int r = p / 56, w = p - r * 56;
        spb[k] = ((r + 1) * 64 + (w + 1)) * PITCH + lq * 16;
    }
    f32x4 acc[2][NPF];
    #pragma unroll
    for (int f = 0; f < 2; ++f)
        #pragma unroll
        for (int k = 0; k < NPF; ++k) acc[f][k] = (f32x4){0.f, 0.f, 0.f, 0.f};
    #pragma unroll 3
    for (int tap = 0; tap < 9; ++tap) {
        const int offb  = ((tap / 3) * 64 + (tap % 3) - 65) * PITCH;
        const int wbase = tap * 16384 + oc0 * 128 + l15 * 128 + lq * 8;
        #pragma unroll
        for (int c = 0; c < 4; ++c) {
            bf16x8 a[2];
            #pragma unroll
            for (int f = 0; f < 2; ++f) {
                const float* p = wf + wbase + f * 2048 + c * 32;
                #pragma unroll
                for (int j = 0; j < 8; ++j) a[f][j] = (__bf16)p[j];
            }
            #pragma unroll
            for (int k = 0; k < NPF; ++k) {
                bf16x8 b = *(const bf16x8*)(xs + spb[k] + offb + c * 64);
                #pragma unroll
                for (int f = 0; f < 2; ++f)
                    acc[f][k] = __builtin_amdgcn_mfma_f32_16x16x32_bf16(a[f], b, acc[f][k], 0, 0, 0);
            }
        }
    }
    #pragma unroll
    for (int f = 0; f < 2; ++f)
        #pragma unroll
        for (int k = 0; k < NPF; ++k) {
            int pos = r0 * 56 + (pf0 + k) * 16 + l15;
            int oc  = oc0 + f * 16 + lq * 4;
            #pragma unroll
            for (int rr = 0; rr < 4; ++rr)
                on[(size_t)(oc + rr) * HW + pos] = acc[f][k][rr];
        }
}

__global__ __launch_bounds__(512, 4) void fb_conv_kernel(const float* __restrict__ x,
                                                         const float* __restrict__ wf,
                                                         float* __restrict__ out) {
    __shared__ __align__(16) unsigned char xs[LDSB];
    const int tid = threadIdx.x, lane = tid & 63, wv = tid >> 6;
    const int bid = blockIdx.x;
    const int swz = (bid & 7) * (NBLK / 8) + (bid >> 3);
    const int n = swz / 28, rp = swz - n * 28, r0 = rp * 2;
    if (wv < 4) {
        const float* xn = x + (size_t)n * 128 * HW;
        const int ar = r0 - 1 + wv, wi = lane - 1;
        const bool v = (ar >= 0) & (ar < IMG_H) & (wi >= 0) & (wi < IMG_W);
        const int gc = min(max(ar, 0), IMG_H - 1) * IMG_W + min(max(wi, 0), IMG_W - 1);
        unsigned char* dst = xs + (wv * 64 + lane) * PITCH;
        #pragma unroll
        for (int cg = 0; cg < 16; ++cg) {
            bf16x8 pk;
            #pragma unroll
            for (int j = 0; j < 8; ++j) {
                float f = xn[(size_t)(cg * 8 + j) * HW + gc];
                pk[j] = (__bf16)(v ? f : 0.f);
            }
            *(bf16x8*)(dst + cg * 16) = pk;
        }
    }
    __syncthreads();
    const int oc0 = (wv & 3) * 32;
    float* on = out + (size_t)n * 128 * HW;
    if (wv < 4) fb_compute<4>(xs, wf, on, oc0, 0, r0, lane);
    else        fb_compute<3>(xs, wf, on, oc0, 4, r0, lane);
}

extern "C" void kernel_launch(void* const* d_in, const int* in_sizes, int n_in,
                              void* d_out, int out_size, void* d_ws, size_t ws_size,
                              hipStream_t stream) {
    const float* x = (const float*)d_in[0];
    const float* w = (const float*)d_in[1];
    float* out = (float*)d_out;

    if (ws_size >= WB_BYTES) {
        unsigned char* wb = (unsigned char*)d_ws;
        wcvt_kernel<<<(WGRAN + 255) / 256, 256, 0, stream>>>(w, wb);
        conv_kernel<<<CBLK, 512, 0, stream>>>(x, wb, out);
    } else {
        fb_conv_kernel<<<NBLK, 512, 0, stream>>>(x, w, out);
    }
}

// Round 20
// 46.637 us; speedup vs baseline: 4.6391x; 1.0515x over previous
//
#include <hip/hip_runtime.h>
#include <hip/hip_bf16.h>

typedef __bf16 bf16x8 __attribute__((ext_vector_type(8)));
typedef float  f32x4  __attribute__((ext_vector_type(4)));

#define HW       3136
#define IMG_W    56
#define IMG_H    56
#define WGRAN    (9*128*16)                // 16B granules in W (18432)
#define WB_BYTES ((size_t)WGRAN*16)        // 294912
#define CBLK     448                       // conv blocks: 14/img, 4 out-rows each
#define SLOTQ    5120                      // 64 cols * 80 B (32ch bf16 + 16B pad)
#define QBUF     (6*SLOTQ)                 // 30720 per quarter buffer
#define LDS_B    (2*QBUF)                  // 61440 -> still 2 blocks/CU

#define AS1 __attribute__((address_space(1)))
#define AS3 __attribute__((address_space(3)))

// ---- weight fp32 -> bf16, fragment-major [tap][q32][c][f][lq][l15] 16B granules ----
__global__ __launch_bounds__(256) void wcvt_kernel(const float* __restrict__ w,
                                                   unsigned char* __restrict__ wb) {
    int i = blockIdx.x * 256 + threadIdx.x;          // one 16B granule each
    if (i >= WGRAN) return;
    const int l15 = i & 15, lq = (i >> 4) & 3, f = (i >> 6) & 1;
    const int c   = (i >> 7) & 3, q32 = (i >> 9) & 3, tap = i >> 11;
    const int oc = q32 * 32 + f * 16 + l15;
    const int ch = c * 32 + lq * 8;
    const float* src = w + (size_t)(tap * 128 + oc) * 128 + ch;
    bf16x8 v;
    #pragma unroll
    for (int j = 0; j < 8; ++j) v[j] = (__bf16)src[j];
    *(bf16x8*)(wb + (size_t)i * 16) = v;
}

// ---- stage one (slot, granule) of channel-quarter Q: 8 coalesced 224B fp32 rows ->
//      cvt -> one ds_write_b128 at pitch-80. Zero borders via mask. ----
template<int Q>
__device__ __forceinline__ void stage_task(unsigned char* xq, const float* __restrict__ xn,
                                           int obase, int s, int g, int lane) {
    const int ar  = obase - 1 + s;                       // absolute image row
    const int arc = min(max(ar, 0), IMG_H - 1);
    const int wcc = min(max(lane - 1, 0), IMG_W - 1);
    const bool v  = (ar >= 0) & (ar < IMG_H) & (lane >= 1) & (lane <= IMG_W);
    const float* bp = xn + (size_t)(Q * 32 + g * 8) * HW + arc * IMG_W + wcc;
    bf16x8 pk;
    #pragma unroll
    for (int j = 0; j < 8; ++j) {
        float f = bp[(size_t)j * HW];
        pk[j] = (__bf16)(v ? f : 0.f);
    }
    *(bf16x8*)(xq + s * SLOTQ + lane * 80 + g * 16) = pk;
}

// ---- compute 9 tap-steps of channel-quarter Q (K=32/tap), accumulating;
//      STG: stage quarter Q+1 into the idle buffer at steps 2/4/6 (1 task each) ----
template<int Q, bool STG>
__device__ __forceinline__ void compute_quarter(const unsigned char* xq, unsigned char* xnext,
                                                const unsigned char* wt,
                                                f32x4 acc[2][7], const int vb[7], int lq,
                                                const float* __restrict__ xn, int obase,
                                                int wv, int lane) {
    bf16x8 aB[2][2];                                     // A ring, 1 tap ahead
    #pragma unroll
    for (int f = 0; f < 2; ++f)
        aB[0][f] = *(const bf16x8*)(wt + (Q * 2 + f) * 1024);

    #pragma unroll
    for (int s = 0; s < 9; ++s) {
        if (s < 8) {                                     // prefetch next tap's A
            #pragma unroll
            for (int f = 0; f < 2; ++f)
                aB[(s + 1) & 1][f] = *(const bf16x8*)(wt + (s + 1) * 32768
                                                      + (Q * 2 + f) * 1024);
        }
        if constexpr (STG) {
            if (s == 2 || s == 4 || s == 6) {            // 3 tasks/wave -> 24 tasks
                int task = wv + 8 * ((s >> 1) - 1);      // 0..23 = 6 slots x 4 granules
                stage_task<(Q + 1) & 3>(xnext, xn, obase, task >> 2, task & 3, lane);
            }
        }
        __builtin_amdgcn_sched_barrier(0);               // pin loads before MFMA cluster

        const int dh = s / 3 - 1, dw = s - (s / 3) * 3 - 1;
        const int offb = dh * SLOTQ + dw * 80 + lq * 16;
        __builtin_amdgcn_s_setprio(1);
        #pragma unroll
        for (int k = 0; k < 7; ++k) {
            bf16x8 b = *(const bf16x8*)(xq + vb[k] + offb);
            acc[0][k] = __builtin_amdgcn_mfma_f32_16x16x32_bf16(aB[s & 1][0], b, acc[0][k], 0, 0, 0);
            acc[1][k] = __builtin_amdgcn_mfma_f32_16x16x32_bf16(aB[s & 1][1], b, acc[1][k], 0, 0, 0);
        }
        __builtin_amdgcn_s_setprio(0);
        __builtin_amdgcn_sched_barrier(0);
    }
}

// ---- conv: 448 blocks x one 4-row tile (224 pos); 8 waves = 4 oc-groups x 2 pos-halves
//      (K=7); channel-QUARTER double-buffered LDS (2 x 30KB) -> staging hidden
//      under compute; 2 blocks/CU, 16 waves/CU ----
__global__ __launch_bounds__(512, 4) void conv_kernel(const float* __restrict__ x,
                                                      const unsigned char* __restrict__ wb,
                                                      float* __restrict__ out) {
    __shared__ __align__(16) unsigned char xs[LDS_B];    // 2 quarter-buffers
    unsigned char* buf0 = xs;
    unsigned char* buf1 = xs + QBUF;
    const int t = threadIdx.x, lane = t & 63, wv = t >> 6;  // 8 waves
    const int l15 = lane & 15, lq = lane >> 4;
    const int b = blockIdx.x;
    const int swz = (b & 7) * 56 + (b >> 3);             // XCD-contiguous: 4 img/XCD
    const int img = swz / 14, loc = swz - img * 14;
    const int obase = loc * 4;                           // out rows obase..obase+3

    const float* xn = x + (size_t)img * 128 * HW;
    const int q32 = wv & 3;                              // 32-oc group
    const int g7  = wv >> 2;                             // pos-half (7 frags)
    const unsigned char* wt = wb + (size_t)q32 * 8192 + lane * 16;

    int vb[7];
    #pragma unroll
    for (int k = 0; k < 7; ++k) {
        int p = (g7 * 7 + k) * 16 + l15;                 // 0..223 tile-local pos
        int pr = p / 56, pc = p - pr * 56;
        vb[k] = (pr + 1) * SLOTQ + (pc + 1) * 80;
    }

    f32x4 acc[2][7];
    #pragma unroll
    for (int f = 0; f < 2; ++f)
        #pragma unroll
        for (int k = 0; k < 7; ++k) acc[f][k] = (f32x4){0.f, 0.f, 0.f, 0.f};

    // prologue: stage quarter 0 (24 tasks, 3/wave)
    #pragma unroll
    for (int i = 0; i < 3; ++i) {
        int task = wv + 8 * i;
        stage_task<0>(buf0, xn, obase, task >> 2, task & 3, lane);
    }
    __syncthreads();

    compute_quarter<0, true >(buf0, buf1, wt, acc, vb, lq, xn, obase, wv, lane);
    __syncthreads();
    compute_quarter<1, true >(buf1, buf0, wt, acc, vb, lq, xn, obase, wv, lane);
    __syncthreads();
    compute_quarter<2, true >(buf0, buf1, wt, acc, vb, lq, xn, obase, wv, lane);
    __syncthreads();
    compute_quarter<3, false>(buf1, buf0, wt, acc, vb, lq, xn, obase, wv, lane);

    // ---- store ----
    float* on = out + (size_t)img * 128 * HW;
    #pragma unroll
    for (int f = 0; f < 2; ++f)
        #pragma unroll
        for (int k = 0; k < 7; ++k) {
            int p = (g7 * 7 + k) * 16 + l15;
            int pr = p / 56, pc = p - pr * 56;
            int pos = (obase + pr) * 56 + pc;
            int oc  = q32 * 32 + f * 16 + lq * 4;
            #pragma unroll
            for (int rr = 0; rr < 4; ++rr)
                on[(size_t)(oc + rr) * HW + pos] = acc[f][k][rr];
        }
}

// ================= fallback (ws too small): self-contained, fp32 weights =================
#define PITCH  272
#define LDSB   (4*64*PITCH)
#define NBLK   896

template<int NPF>
__device__ __forceinline__ void fb_compute(const unsigned char* xs, const float* wf,
                                           float* on, int oc0, int pf0, int r0, int lane) {
    const int l15 = lane & 15, lq = lane >> 4;
    int spb[NPF];
    #pragma unroll
    for (int k = 0; k < NPF; ++k) {
        int p = (pf0 + k) * 16 + l15;
        int r = p / 56, w = p - r * 56;
        spb[k] = ((r + 1) * 64 + (w + 1)) * PITCH + lq * 16;
    }
    f32x4 acc[2][NPF];
    #pragma unroll
    for (int f = 0; f < 2; ++f)
        #pragma unroll
        for (int k = 0; k < NPF; ++k) acc[f][k] = (f32x4){0.f, 0.f, 0.f, 0.f};
    #pragma unroll 3
    for (int tap = 0; tap < 9; ++tap) {
        const int offb  = ((tap / 3) * 64 + (tap % 3) - 65) * PITCH;
        const int wbase = tap * 16384 + oc0 * 128 + l15 * 128 + lq * 8;
        #pragma unroll
        for (int c = 0; c < 4; ++c) {
            bf16x8 a[2];
            #pragma unroll
            for (int f = 0; f < 2; ++f) {
                const float* p = wf + wbase + f * 2048 + c * 32;
                #pragma unroll
                for (int j = 0; j < 8; ++j) a[f][j] = (__bf16)p[j];
            }
            #pragma unroll
            for (int k = 0; k < NPF; ++k) {
                bf16x8 b = *(const bf16x8*)(xs + spb[k] + offb + c * 64);
                #pragma unroll
                for (int f = 0; f < 2; ++f)
                    acc[f][k] = __builtin_amdgcn_mfma_f32_16x16x32_bf16(a[f], b, acc[f][k], 0, 0, 0);
            }
        }
    }
    #pragma unroll
    for (int f = 0; f < 2; ++f)
        #pragma unroll
        for (int k = 0; k < NPF; ++k) {
            int pos = r0 * 56 + (pf0 + k) * 16 + l15;
            int oc  = oc0 + f * 16 + lq * 4;
            #pragma unroll
            for (int rr = 0; rr < 4; ++rr)
                on[(size_t)(oc + rr) * HW + pos] = acc[f][k][rr];
        }
}

__global__ __launch_bounds__(512, 4) void fb_conv_kernel(const float* __restrict__ x,
                                                         const float* __restrict__ wf,
                                                         float* __restrict__ out) {
    __shared__ __align__(16) unsigned char xs[LDSB];
    const int tid = threadIdx.x, lane = tid & 63, wv = tid >> 6;
    const int bid = blockIdx.x;
    const int swz = (bid & 7) * (NBLK / 8) + (bid >> 3);
    const int n = swz / 28, rp = swz - n * 28, r0 = rp * 2;
    if (wv < 4) {
        const float* xn = x + (size_t)n * 128 * HW;
        const int ar = r0 - 1 + wv, wi = lane - 1;
        const bool v = (ar >= 0) & (ar < IMG_H) & (wi >= 0) & (wi < IMG_W);
        const int gc = min(max(ar, 0), IMG_H - 1) * IMG_W + min(max(wi, 0), IMG_W - 1);
        unsigned char* dst = xs + (wv * 64 + lane) * PITCH;
        #pragma unroll
        for (int cg = 0; cg < 16; ++cg) {
            bf16x8 pk;
            #pragma unroll
            for (int j = 0; j < 8; ++j) {
                float f = xn[(size_t)(cg * 8 + j) * HW + gc];
                pk[j] = (__bf16)(v ? f : 0.f);
            }
            *(bf16x8*)(dst + cg * 16) = pk;
        }
    }
    __syncthreads();
    const int oc0 = (wv & 3) * 32;
    float* on = out + (size_t)n * 128 * HW;
    if (wv < 4) fb_compute<4>(xs, wf, on, oc0, 0, r0, lane);
    else        fb_compute<3>(xs, wf, on, oc0, 4, r0, lane);
}

extern "C" void kernel_launch(void* const* d_in, const int* in_sizes, int n_in,
                              void* d_out, int out_size, void* d_ws, size_t ws_size,
                              hipStream_t stream) {
    const float* x = (const float*)d_in[0];
    const float* w = (const float*)d_in[1];
    float* out = (float*)d_out;

    if (ws_size >= WB_BYTES) {
        unsigned char* wb = (unsigned char*)d_ws;
        wcvt_kernel<<<(WGRAN + 255) / 256, 256, 0, stream>>>(w, wb);
        conv_kernel<<<CBLK, 512, 0, stream>>>(x, wb, out);
    } else {
        fb_conv_kernel<<<NBLK, 512, 0, stream>>>(x, w, out);
    }
}

// Round 21
// 45.639 us; speedup vs baseline: 4.7406x; 1.0219x over previous
//
#include <hip/hip_runtime.h>
#include <hip/hip_bf16.h>

typedef __bf16 bf16x8 __attribute__((ext_vector_type(8)));
typedef __bf16 bf16x4 __attribute__((ext_vector_type(4)));
typedef float  f32x4  __attribute__((ext_vector_type(4)));

#define HW       3136
#define IMG_W    56
#define IMG_H    56
#define WGRAN    (9*128*16)                // 16B granules in W (18432)
#define WB_BYTES ((size_t)WGRAN*16)        // 294912
#define CBLK     448                       // conv blocks: 14/img, 4 out-rows each
#define SLOTQ    5120                      // 64 cols * 80 B (32ch bf16 + 16B pad)
#define QBUF     (6*SLOTQ)                 // 30720 per quarter buffer
#define LDS_B    (2*QBUF)                  // 61440 -> still 2 blocks/CU

#define AS1 __attribute__((address_space(1)))
#define AS3 __attribute__((address_space(3)))

// ---- weight fp32 -> bf16, fragment-major [tap][q32][c][f][lq][l15] 16B granules ----
__global__ __launch_bounds__(256) void wcvt_kernel(const float* __restrict__ w,
                                                   unsigned char* __restrict__ wb) {
    int i = blockIdx.x * 256 + threadIdx.x;          // one 16B granule each
    if (i >= WGRAN) return;
    const int l15 = i & 15, lq = (i >> 4) & 3, f = (i >> 6) & 1;
    const int c   = (i >> 7) & 3, q32 = (i >> 9) & 3, tap = i >> 11;
    const int oc = q32 * 32 + f * 16 + l15;
    const int ch = c * 32 + lq * 8;
    const float* src = w + (size_t)(tap * 128 + oc) * 128 + ch;
    bf16x8 v;
    #pragma unroll
    for (int j = 0; j < 8; ++j) v[j] = (__bf16)src[j];
    *(bf16x8*)(wb + (size_t)i * 16) = v;
}

// ---- full stage task (prologue only): 8 fp32 rows -> cvt -> ds_write_b128 ----
template<int Q>
__device__ __forceinline__ void stage_task(unsigned char* xq, const float* __restrict__ xn,
                                           int obase, int s, int g, int lane) {
    const int ar  = obase - 1 + s;                       // absolute image row
    const int arc = min(max(ar, 0), IMG_H - 1);
    const int wcc = min(max(lane - 1, 0), IMG_W - 1);
    const bool v  = (ar >= 0) & (ar < IMG_H) & (lane >= 1) & (lane <= IMG_W);
    const float* bp = xn + (size_t)(Q * 32 + g * 8) * HW + arc * IMG_W + wcc;
    bf16x8 pk;
    #pragma unroll
    for (int j = 0; j < 8; ++j) {
        float f = bp[(size_t)j * HW];
        pk[j] = (__bf16)(v ? f : 0.f);
    }
    *(bf16x8*)(xq + s * SLOTQ + lane * 80 + g * 16) = pk;
}

// ---- half stage task (in-compute): 4 fp32 rows -> cvt -> ds_write_b64 ----
//      halves peak live staging state vs full task (spill avoidance)
template<int Q>
__device__ __forceinline__ void stage_half(unsigned char* xq, const float* __restrict__ xn,
                                           int obase, int s, int g, int h, int lane) {
    const int ar  = obase - 1 + s;
    const int arc = min(max(ar, 0), IMG_H - 1);
    const int wcc = min(max(lane - 1, 0), IMG_W - 1);
    const bool v  = (ar >= 0) & (ar < IMG_H) & (lane >= 1) & (lane <= IMG_W);
    const float* bp = xn + (size_t)(Q * 32 + g * 8 + h * 4) * HW + arc * IMG_W + wcc;
    bf16x4 pk;
    #pragma unroll
    for (int j = 0; j < 4; ++j) {
        float f = bp[(size_t)j * HW];
        pk[j] = (__bf16)(v ? f : 0.f);
    }
    *(bf16x4*)(xq + s * SLOTQ + lane * 80 + g * 16 + h * 8) = pk;
}

// ---- compute 9 tap-steps of channel-quarter Q (K=32/tap), accumulating;
//      STG: one half-task per wave at steps 1..6 -> 48 half-tasks = quarter Q+1 ----
template<int Q, bool STG>
__device__ __forceinline__ void compute_quarter(const unsigned char* xq, unsigned char* xnext,
                                                const unsigned char* wt,
                                                f32x4 acc[2][7], const int vb[7], int lq,
                                                const float* __restrict__ xn, int obase,
                                                int wv, int lane) {
    bf16x8 aB[2][2];                                     // A ring, 1 tap ahead
    #pragma unroll
    for (int f = 0; f < 2; ++f)
        aB[0][f] = *(const bf16x8*)(wt + (Q * 2 + f) * 1024);

    #pragma unroll
    for (int s = 0; s < 9; ++s) {
        if (s < 8) {                                     // prefetch next tap's A
            #pragma unroll
            for (int f = 0; f < 2; ++f)
                aB[(s + 1) & 1][f] = *(const bf16x8*)(wt + (s + 1) * 32768
                                                      + (Q * 2 + f) * 1024);
        }
        if constexpr (STG) {
            if (s >= 1 && s <= 6) {                      // slot s-1, g=wv>>1, h=wv&1
                stage_half<(Q + 1) & 3>(xnext, xn, obase, s - 1, wv >> 1, wv & 1, lane);
            }
        }
        __builtin_amdgcn_sched_barrier(0);               // pin loads before MFMA cluster

        const int dh = s / 3 - 1, dw = s - (s / 3) * 3 - 1;
        const int offb = dh * SLOTQ + dw * 80 + lq * 16;
        __builtin_amdgcn_s_setprio(1);
        #pragma unroll
        for (int k = 0; k < 7; ++k) {
            bf16x8 b = *(const bf16x8*)(xq + vb[k] + offb);
            acc[0][k] = __builtin_amdgcn_mfma_f32_16x16x32_bf16(aB[s & 1][0], b, acc[0][k], 0, 0, 0);
            acc[1][k] = __builtin_amdgcn_mfma_f32_16x16x32_bf16(aB[s & 1][1], b, acc[1][k], 0, 0, 0);
        }
        __builtin_amdgcn_s_setprio(0);
        __builtin_amdgcn_sched_barrier(0);
    }
}

// ---- conv: 448 blocks x one 4-row tile (224 pos); 8 waves = 4 oc-groups x 2 pos-halves
//      (K=7); channel-QUARTER double-buffered LDS (2 x 30KB); 2 blocks/CU ----
__global__ __launch_bounds__(512, 4) void conv_kernel(const float* __restrict__ x,
                                                      const unsigned char* __restrict__ wb,
                                                      float* __restrict__ out) {
    __shared__ __align__(16) unsigned char xs[LDS_B];    // 2 quarter-buffers
    unsigned char* buf0 = xs;
    unsigned char* buf1 = xs + QBUF;
    const int t = threadIdx.x, lane = t & 63, wv = t >> 6;  // 8 waves
    const int l15 = lane & 15, lq = lane >> 4;
    const int b = blockIdx.x;
    const int swz = (b & 7) * 56 + (b >> 3);             // XCD-contiguous: 4 img/XCD
    const int img = swz / 14, loc = swz - img * 14;
    const int obase = loc * 4;                           // out rows obase..obase+3

    const float* xn = x + (size_t)img * 128 * HW;
    const int q32 = wv & 3;                              // 32-oc group
    const int g7  = wv >> 2;                             // pos-half (7 frags)
    const unsigned char* wt = wb + (size_t)q32 * 8192 + lane * 16;

    int vb[7];
    #pragma unroll
    for (int k = 0; k < 7; ++k) {
        int p = (g7 * 7 + k) * 16 + l15;                 // 0..223 tile-local pos
        int pr = p / 56, pc = p - pr * 56;
        vb[k] = (pr + 1) * SLOTQ + (pc + 1) * 80;
    }

    f32x4 acc[2][7];
    #pragma unroll
    for (int f = 0; f < 2; ++f)
        #pragma unroll
        for (int k = 0; k < 7; ++k) acc[f][k] = (f32x4){0.f, 0.f, 0.f, 0.f};

    // prologue: stage quarter 0 (24 tasks, 3/wave)
    #pragma unroll
    for (int i = 0; i < 3; ++i) {
        int task = wv + 8 * i;
        stage_task<0>(buf0, xn, obase, task >> 2, task & 3, lane);
    }
    __syncthreads();

    compute_quarter<0, true >(buf0, buf1, wt, acc, vb, lq, xn, obase, wv, lane);
    __syncthreads();
    compute_quarter<1, true >(buf1, buf0, wt, acc, vb, lq, xn, obase, wv, lane);
    __syncthreads();
    compute_quarter<2, true >(buf0, buf1, wt, acc, vb, lq, xn, obase, wv, lane);
    __syncthreads();
    compute_quarter<3, false>(buf1, buf0, wt, acc, vb, lq, xn, obase, wv, lane);

    // ---- store ----
    float* on = out + (size_t)img * 128 * HW;
    #pragma unroll
    for (int f = 0; f < 2; ++f)
        #pragma unroll
        for (int k = 0; k < 7; ++k) {
            int p = (g7 * 7 + k) * 16 + l15;
            int pr = p / 56, pc = p - pr * 56;
            int pos = (obase + pr) * 56 + pc;
            int oc  = q32 * 32 + f * 16 + lq * 4;
            #pragma unroll
            for (int rr = 0; rr < 4; ++rr)
                on[(size_t)(oc + rr) * HW + pos] = acc[f][k][rr];
        }
}

// ================= fallback (ws too small): self-contained, fp32 weights =================
#define PITCH  272
#define LDSB   (4*64*PITCH)
#define NBLK   896

template<int NPF>
__device__ __forceinline__ void fb_compute(const unsigned char* xs, const float* wf,
                                           float* on, int oc0, int pf0, int r0, int lane) {
    const int l15 = lane & 15, lq = lane >> 4;
    int spb[NPF];
    #pragma unroll
    for (int k = 0; k < NPF; ++k) {
        int p = (pf0 + k) * 16 + l15;
        int r = p / 56, w = p - r * 56;
        spb[k] = ((r + 1) * 64 + (w + 1)) * PITCH + lq * 16;
    }
    f32x4 acc[2][NPF];
    #pragma unroll
    for (int f = 0; f < 2; ++f)
        #pragma unroll
        for (int k = 0; k < NPF; ++k) acc[f][k] = (f32x4){0.f, 0.f, 0.f, 0.f};
    #pragma unroll 3
    for (int tap = 0; tap < 9; ++tap) {
        const int offb  = ((tap / 3) * 64 + (tap % 3) - 65) * PITCH;
        const int wbase = tap * 16384 + oc0 * 128 + l15 * 128 + lq * 8;
        #pragma unroll
        for (int c = 0; c < 4; ++c) {
            bf16x8 a[2];
            #pragma unroll
            for (int f = 0; f < 2; ++f) {
                const float* p = wf + wbase + f * 2048 + c * 32;
                #pragma unroll
                for (int j = 0; j < 8; ++j) a[f][j] = (__bf16)p[j];
            }
            #pragma unroll
            for (int k = 0; k < NPF; ++k) {
                bf16x8 b = *(const bf16x8*)(xs + spb[k] + offb + c * 64);
                #pragma unroll
                for (int f = 0; f < 2; ++f)
                    acc[f][k] = __builtin_amdgcn_mfma_f32_16x16x32_bf16(a[f], b, acc[f][k], 0, 0, 0);
            }
        }
    }
    #pragma unroll
    for (int f = 0; f < 2; ++f)
        #pragma unroll
        for (int k = 0; k < NPF; ++k) {
            int pos = r0 * 56 + (pf0 + k) * 16 + l15;
            int oc  = oc0 + f * 16 + lq * 4;
            #pragma unroll
            for (int rr = 0; rr < 4; ++rr)
                on[(size_t)(oc + rr) * HW + pos] = acc[f][k][rr];
        }
}

__global__ __launch_bounds__(512, 4) void fb_conv_kernel(const float* __restrict__ x,
                                                         const float* __restrict__ wf,
                                                         float* __restrict__ out) {
    __shared__ __align__(16) unsigned char xs[LDSB];
    const int tid = threadIdx.x, lane = tid & 63, wv = tid >> 6;
    const int bid = blockIdx.x;
    const int swz = (bid & 7) * (NBLK / 8) + (bid >> 3);
    const int n = swz / 28, rp = swz - n * 28, r0 = rp * 2;
    if (wv < 4) {
        const float* xn = x + (size_t)n * 128 * HW;
        const int ar = r0 - 1 + wv, wi = lane - 1;
        const bool v = (ar >= 0) & (ar < IMG_H) & (wi >= 0) & (wi < IMG_W);
        const int gc = min(max(ar, 0), IMG_H - 1) * IMG_W + min(max(wi, 0), IMG_W - 1);
        unsigned char* dst = xs + (wv * 64 + lane) * PITCH;
        #pragma unroll
        for (int cg = 0; cg < 16; ++cg) {
            bf16x8 pk;
            #pragma unroll
            for (int j = 0; j < 8; ++j) {
                float f = xn[(size_t)(cg * 8 + j) * HW + gc];
                pk[j] = (__bf16)(v ? f : 0.f);
            }
            *(bf16x8*)(dst + cg * 16) = pk;
        }
    }
    __syncthreads();
    const int oc0 = (wv & 3) * 32;
    float* on = out + (size_t)n * 128 * HW;
    if (wv < 4) fb_compute<4>(xs, wf, on, oc0, 0, r0, lane);
    else        fb_compute<3>(xs, wf, on, oc0, 4, r0, lane);
}

extern "C" void kernel_launch(void* const* d_in, const int* in_sizes, int n_in,
                              void* d_out, int out_size, void* d_ws, size_t ws_size,
                              hipStream_t stream) {
    const float* x = (const float*)d_in[0];
    const float* w = (const float*)d_in[1];
    float* out = (float*)d_out;

    if (ws_size >= WB_BYTES) {
        unsigned char* wb = (unsigned char*)d_ws;
        wcvt_kernel<<<(WGRAN + 255) / 256, 256, 0, stream>>>(w, wb);
        conv_kernel<<<CBLK, 512, 0, stream>>>(x, wb, out);
    } else {
        fb_conv_kernel<<<NBLK, 512, 0, stream>>>(x, w, out);
    }
}